// Round 2
// baseline (906.375 us; speedup 1.0000x reference)
//
#include <hip/hip_runtime.h>
#include <math.h>

// Problem constants
#define TB 4
#define TS 2048
#define TE 1024
#define TH 16
#define TD 64
#define TM_ (TB*TS)   // 8192 rows

// Workspace float offsets
#define WS_Q   0          // Q fp32 [bh][s][64] -> in-place split [bh][s][hi64|lo64] bf16
#define WS_K   8388608    // K likewise
#define WS_L   16777216   // softmax denominators [bh][s]
#define WS_TAB 16908288   // cos/sin table [s][32][2]

typedef __attribute__((ext_vector_type(8))) short bf16x8;  // 8 bf16 = 4 VGPRs
typedef __attribute__((ext_vector_type(4))) float f32x4;

static __device__ inline unsigned fbits(float x) {
    union { float f; unsigned u; } v; v.f = x; return v.u;
}
static __device__ inline float bits2f(unsigned u) {
    union { unsigned u; float f; } v; v.u = u; return v.f;
}
// pack [bf16(a), bf16(b)] (round-half-up) into one dword, a in low half
static __device__ inline unsigned pack_rhu(float a, float b) {
    return __builtin_amdgcn_perm(fbits(b) + 0x8000u, fbits(a) + 0x8000u, 0x07060302u);
}
static __device__ inline short bf16s(float x) {
    return (short)((fbits(x) + 0x8000u) >> 16);
}
// FIXED hi/lo split: lo is computed against the ROUNDED hi (old version used the
// truncated hi -> hi+lo overshot by one hi-ulp for half the inputs).
static __device__ inline void split2r(float x0, float x1, unsigned& hp, unsigned& lp) {
    unsigned u0 = fbits(x0) + 0x8000u, u1 = fbits(x1) + 0x8000u;
    hp = __builtin_amdgcn_perm(u1, u0, 0x07060302u);
    float h0 = bits2f(u0 & 0xffff0000u);   // rounded hi as float
    float h1 = bits2f(u1 & 0xffff0000u);
    lp = pack_rhu(x0 - h0, x1 - h1);
}

// ----------------------------------------------------------------------------
// split_rows: src [nrows][1024] fp32 -> dst rows of 2048 shorts:
//   [ hi: kt*64 + (ch^(row&7))*8 + k%8  |  lo at +1024 shorts ]
// kt = k/64 (16 tiles of BK=64), ch = (k%64)/8. One thread per (row, kt).
// ----------------------------------------------------------------------------
__global__ __launch_bounds__(256, 4)
void split_rows(const float* __restrict__ src, unsigned* __restrict__ dst)
{
    const int idx = blockIdx.x * 256 + threadIdx.x;
    const int kt  = idx & 15;
    const int row = idx >> 4;
    const uint4* sp = (const uint4*)(src + (size_t)row * 1024 + kt * 64);
    unsigned* dp = dst + (size_t)row * 1024 + kt * 32;       // hi base (dwords)
    const int key = row & 7;
    #pragma unroll
    for (int ch = 0; ch < 8; ++ch) {
        uint4 v0 = sp[ch * 2 + 0];
        uint4 v1 = sp[ch * 2 + 1];
        unsigned h[4], l[4];
        split2r(bits2f(v0.x), bits2f(v0.y), h[0], l[0]);
        split2r(bits2f(v0.z), bits2f(v0.w), h[1], l[1]);
        split2r(bits2f(v1.x), bits2f(v1.y), h[2], l[2]);
        split2r(bits2f(v1.z), bits2f(v1.w), h[3], l[3]);
        const int slot = ch ^ key;
        *(uint4*)(dp + slot * 4)       = make_uint4(h[0], h[1], h[2], h[3]);
        *(uint4*)(dp + 512 + slot * 4) = make_uint4(l[0], l[1], l[2], l[3]);
    }
}

// ----------------------------------------------------------------------------
// GEMM v3: C[m,n] = sum_k X[m,k]*W[n,k] + bias[n], split-bf16 3-term MFMA.
// Inputs pre-split/swizzled (split_rows layout). 128x128 tile, BK=64, 4 waves.
// MODE 0: fp32 out[m*N+n]; MODE 1: fp32 [B,H,S,D]; MODE 2: bf16 V^T swizzled tiles
// ----------------------------------------------------------------------------
template<int MODE>
__global__ __launch_bounds__(256, 2)
void gemm3(const unsigned* __restrict__ X2, const unsigned* __restrict__ W2,
           const float* __restrict__ bias, float* __restrict__ out)
{
    __shared__ short Ah[128 * 64], Al[128 * 64], Bh[128 * 64], Bl[128 * 64];

    const int tid  = threadIdx.x;
    const int lane = tid & 63;
    const int wv   = tid >> 6;
    const int t16  = lane & 15;
    const int quad = lane >> 4;
    const int wm   = (wv >> 1) * 64;
    const int wn   = (wv & 1) * 64;
    const int m0 = blockIdx.y * 128;
    const int n0 = blockIdx.x * 128;

    const int cx0 = ((quad) ^ (t16 & 7)) * 8;       // ks=0 chunk offset (shorts)
    const int cx1 = ((4 + quad) ^ (t16 & 7)) * 8;   // ks=1

    f32x4 acc[4][4];
    #pragma unroll
    for (int i = 0; i < 4; ++i)
        #pragma unroll
        for (int j = 0; j < 4; ++j) acc[i][j] = (f32x4){0.f, 0.f, 0.f, 0.f};

    int srow[4], ssl[4];
    #pragma unroll
    for (int i = 0; i < 4; ++i) {
        const int p = i * 256 + tid;
        srow[i] = p >> 3;
        ssl[i]  = (p ^ (p >> 3)) & 7;
    }

    for (int kt = 0; kt < 16; ++kt) {
        __syncthreads();
        #pragma unroll
        for (int i = 0; i < 4; ++i) {
            const size_t xa = (size_t)(m0 + srow[i]) * 1024 + kt * 32 + ssl[i] * 4;
            *(uint4*)&Ah[srow[i] * 64 + ssl[i] * 8] = *(const uint4*)(X2 + xa);
            *(uint4*)&Al[srow[i] * 64 + ssl[i] * 8] = *(const uint4*)(X2 + xa + 512);
            const size_t wa = (size_t)(n0 + srow[i]) * 1024 + kt * 32 + ssl[i] * 4;
            *(uint4*)&Bh[srow[i] * 64 + ssl[i] * 8] = *(const uint4*)(W2 + wa);
            *(uint4*)&Bl[srow[i] * 64 + ssl[i] * 8] = *(const uint4*)(W2 + wa + 512);
        }
        __syncthreads();
        #pragma unroll
        for (int ks = 0; ks < 2; ++ks) {
            const int cx = ks ? cx1 : cx0;
            bf16x8 ah[4], al[4], bh[4], bl[4];
            #pragma unroll
            for (int i = 0; i < 4; ++i) {
                ah[i] = *(const bf16x8*)&Ah[(wm + i * 16 + t16) * 64 + cx];
                al[i] = *(const bf16x8*)&Al[(wm + i * 16 + t16) * 64 + cx];
                bh[i] = *(const bf16x8*)&Bh[(wn + i * 16 + t16) * 64 + cx];
                bl[i] = *(const bf16x8*)&Bl[(wn + i * 16 + t16) * 64 + cx];
            }
            #pragma unroll
            for (int i = 0; i < 4; ++i)
                #pragma unroll
                for (int j = 0; j < 4; ++j) {
                    acc[i][j] = __builtin_amdgcn_mfma_f32_16x16x32_bf16(ah[i], bh[j], acc[i][j], 0, 0, 0);
                    acc[i][j] = __builtin_amdgcn_mfma_f32_16x16x32_bf16(al[i], bh[j], acc[i][j], 0, 0, 0);
                    acc[i][j] = __builtin_amdgcn_mfma_f32_16x16x32_bf16(ah[i], bl[j], acc[i][j], 0, 0, 0);
                }
        }
    }

    if (MODE == 2) {
        // bf16 V^T, swizzled tiles: [bh][stile][d][slot*8 + s%8], slot = ((s%64)/8)^(d&7)
        short* o16 = (short*)out;
        const int b = m0 >> 11;
        const int stile = ((m0 & 2047) + wm) >> 6;
        #pragma unroll
        for (int j = 0; j < 4; ++j) {
            const int n = n0 + wn + j * 16 + t16;
            const int h = n >> 6, d = n & 63;
            const float bv = bias[n];
            const size_t dbase = (((size_t)(b * TH + h) * 32 + stile) * 64 + d) * 64;
            #pragma unroll
            for (int i = 0; i < 4; ++i) {
                const int chunk = 2 * i + (quad >> 1);
                const int slot = chunk ^ (d & 7);
                uint2 p = make_uint2(pack_rhu(acc[i][j][0] + bv, acc[i][j][1] + bv),
                                     pack_rhu(acc[i][j][2] + bv, acc[i][j][3] + bv));
                *(uint2*)(o16 + dbase + slot * 8 + (quad & 1) * 4) = p;
            }
        }
        return;
    }

    #pragma unroll
    for (int j = 0; j < 4; ++j) {
        const int n = n0 + wn + j * 16 + t16;
        const float bv = bias[n];
        if (MODE == 0) {
            #pragma unroll
            for (int i = 0; i < 4; ++i)
                #pragma unroll
                for (int r = 0; r < 4; ++r) {
                    const int m = m0 + wm + i * 16 + quad * 4 + r;
                    out[(size_t)m * TE + n] = acc[i][j][r] + bv;
                }
        } else {
            const int h = n >> 6, d = n & 63;
            #pragma unroll
            for (int i = 0; i < 4; ++i)
                #pragma unroll
                for (int r = 0; r < 4; ++r) {
                    const int m = m0 + wm + i * 16 + quad * 4 + r;
                    const int bb_ = m >> 11, s = m & 2047;
                    out[((size_t)(bb_ * TH + h) * TS + s) * TD + d] = acc[i][j][r] + bv;
                }
        }
    }
}

// ----------------------------------------------------------------------------
// RoPE table (unchanged)
// ----------------------------------------------------------------------------
__global__ void rope_table(float* __restrict__ tab)
{
    const int idx = blockIdx.x * 256 + threadIdx.x;
    const int d = idx & 31, s = idx >> 5;
    const float e = (float)(2 * d) / 64.0f;
    const float inv = 1.0f / powf(10000.0f, e);
    const float a = (float)s * inv;
    tab[2 * idx + 0] = cosf(a);
    tab[2 * idx + 1] = sinf(a);
}

// ----------------------------------------------------------------------------
// rope_split: in-place over fp32 [bh][s][64]; applies RoPE (+ Q scale), then
// hi/lo bf16 split into [bh][s][hi 64sh (chunk^(s&7)) | lo 64sh]. One thread
// owns one full row -> in-place safe.
// ----------------------------------------------------------------------------
__global__ __launch_bounds__(256, 2)
void rope_split(float* __restrict__ Q, float* __restrict__ Kv,
                const float* __restrict__ tab)
{
    const int idx = blockIdx.x * 256 + threadIdx.x;    // 262144 total
    const int s  = idx & 2047;
    const int bh = (idx >> 11) & 63;
    const int qk = idx >> 17;
    float* P = qk ? Kv : Q;
    const float scale = qk ? 1.0f : (0.125f * 1.44269504f);
    unsigned* rp = (unsigned*)(P + ((size_t)bh * TS + s) * 64);

    unsigned xu[64];
    #pragma unroll
    for (int i = 0; i < 16; ++i) {
        uint4 v = *(const uint4*)(rp + i * 4);
        xu[4 * i + 0] = v.x; xu[4 * i + 1] = v.y;
        xu[4 * i + 2] = v.z; xu[4 * i + 3] = v.w;
    }
    const float* tb = tab + (size_t)s * 64;
    #pragma unroll
    for (int d = 0; d < 32; ++d) {
        const float c = tb[2 * d], sn = tb[2 * d + 1];
        const float x0 = bits2f(xu[d]), x1 = bits2f(xu[d + 32]);
        xu[d]      = fbits((x0 * c - x1 * sn) * scale);
        xu[d + 32] = fbits((x1 * c + x0 * sn) * scale);
    }
    const int key = s & 7;
    #pragma unroll
    for (int ch = 0; ch < 8; ++ch) {
        unsigned h[4], l[4];
        #pragma unroll
        for (int p = 0; p < 4; ++p)
            split2r(bits2f(xu[ch * 8 + 2 * p]), bits2f(xu[ch * 8 + 2 * p + 1]), h[p], l[p]);
        const int slot = ch ^ key;
        *(uint4*)(rp + slot * 4)      = make_uint4(h[0], h[1], h[2], h[3]);   // hi: dwords [0,32)
        *(uint4*)(rp + 32 + slot * 4) = make_uint4(l[0], l[1], l[2], l[3]);   // lo: dwords [32,64)
    }
}

// ----------------------------------------------------------------------------
// Flash attention: pre-split swizzled bf16 K/Q, swizzled bf16 V^T tiles.
// Staging = pure 16B copies. Ps in XOR-swizzled layout (2-way writes = free).
// Emits O directly in split-bf16 layout for the Wo GEMM.
// ----------------------------------------------------------------------------
__global__ __launch_bounds__(512, 6)
void attn_flash(const short* __restrict__ Qs, const short* __restrict__ Ks,
                const short* __restrict__ VT, short* __restrict__ O,
                float* __restrict__ Ls)
{
    __shared__ short KhL[4096], KlL[4096], VtL[4096];   // [64 rows][64], swizzled
    __shared__ short PsL[8192];                          // [128 rows][64], swizzled

    const int tid  = threadIdx.x;
    const int lane = tid & 63;
    const int wv   = tid >> 6;        // wave 0..7
    const int t16  = lane & 15;
    const int quad = lane >> 4;
    const int q0w  = wv * 16;

    const int q0 = blockIdx.x * 128;
    const int h = blockIdx.y, b = blockIdx.z;
    const int bh = b * TH + h;

    const int cx0 = ((quad) ^ (t16 & 7)) * 8;
    const int cx1 = ((4 + quad) ^ (t16 & 7)) * 8;

    // Q fragments (scaled hi/lo baked by rope_split)
    bf16x8 qfh[2], qfl[2];
    {
        const short* qrow = Qs + ((size_t)bh * TS + q0 + q0w + t16) * 128;
        qfh[0] = *(const bf16x8*)(qrow + cx0);
        qfh[1] = *(const bf16x8*)(qrow + cx1);
        qfl[0] = *(const bf16x8*)(qrow + 64 + cx0);
        qfl[1] = *(const bf16x8*)(qrow + 64 + cx1);
    }

    float lsum[4] = {0.f, 0.f, 0.f, 0.f};
    f32x4 o_acc[4];
    #pragma unroll
    for (int dt = 0; dt < 4; ++dt) o_acc[dt] = (f32x4){0.f, 0.f, 0.f, 0.f};

    const int srow = tid >> 3;
    const int ssl  = (tid ^ srow) & 7;
    const short* kbase = Ks + (size_t)bh * TS * 128;
    const short* vbase = VT + (size_t)bh * 131072;

    for (int j0 = 0; j0 < TS; j0 += 64) {
        __syncthreads();
        {
            const short* krow = kbase + (size_t)(j0 + srow) * 128;
            *(uint4*)&KhL[srow * 64 + ssl * 8] = *(const uint4*)(krow + ssl * 8);
            *(uint4*)&KlL[srow * 64 + ssl * 8] = *(const uint4*)(krow + 64 + ssl * 8);
            *(uint4*)&VtL[tid * 8] = *(const uint4*)(vbase + (j0 << 6) + tid * 8);
        }
        __syncthreads();

        // ---- scores: 3-term split QK^T ----
        f32x4 sc[4];
        #pragma unroll
        for (int t = 0; t < 4; ++t) sc[t] = (f32x4){0.f, 0.f, 0.f, 0.f};
        #pragma unroll
        for (int t = 0; t < 4; ++t) {
            const int rb = (t * 16 + t16) * 64;
            bf16x8 kh0 = *(const bf16x8*)&KhL[rb + cx0];
            bf16x8 kl0 = *(const bf16x8*)&KlL[rb + cx0];
            sc[t] = __builtin_amdgcn_mfma_f32_16x16x32_bf16(qfh[0], kh0, sc[t], 0, 0, 0);
            sc[t] = __builtin_amdgcn_mfma_f32_16x16x32_bf16(qfh[0], kl0, sc[t], 0, 0, 0);
            sc[t] = __builtin_amdgcn_mfma_f32_16x16x32_bf16(qfl[0], kh0, sc[t], 0, 0, 0);
            bf16x8 kh1 = *(const bf16x8*)&KhL[rb + cx1];
            bf16x8 kl1 = *(const bf16x8*)&KlL[rb + cx1];
            sc[t] = __builtin_amdgcn_mfma_f32_16x16x32_bf16(qfh[1], kh1, sc[t], 0, 0, 0);
            sc[t] = __builtin_amdgcn_mfma_f32_16x16x32_bf16(qfh[1], kl1, sc[t], 0, 0, 0);
            sc[t] = __builtin_amdgcn_mfma_f32_16x16x32_bf16(qfl[1], kh1, sc[t], 0, 0, 0);
        }

        // ---- p = exp2(s'), accumulate l, write P to swizzled LDS ----
        #pragma unroll
        for (int t = 0; t < 4; ++t) {
            float p0 = __builtin_amdgcn_exp2f(sc[t][0]);
            float p1 = __builtin_amdgcn_exp2f(sc[t][1]);
            float p2 = __builtin_amdgcn_exp2f(sc[t][2]);
            float p3 = __builtin_amdgcn_exp2f(sc[t][3]);
            lsum[0] += p0; lsum[1] += p1; lsum[2] += p2; lsum[3] += p3;
            const int cb = 2 * t + (t16 >> 3);
            const int co = t16 & 7;
            PsL[(q0w + quad * 4 + 0) * 64 + ((cb ^ ((quad * 4 + 0) & 7)) * 8) + co] = bf16s(p0);
            PsL[(q0w + quad * 4 + 1) * 64 + ((cb ^ ((quad * 4 + 1) & 7)) * 8) + co] = bf16s(p1);
            PsL[(q0w + quad * 4 + 2) * 64 + ((cb ^ ((quad * 4 + 2) & 7)) * 8) + co] = bf16s(p2);
            PsL[(q0w + quad * 4 + 3) * 64 + ((cb ^ ((quad * 4 + 3) & 7)) * 8) + co] = bf16s(p3);
        }

        // ---- PV ----
        {
            const int pr = (q0w + t16) * 64;
            bf16x8 pa0 = *(const bf16x8*)&PsL[pr + cx0];
            #pragma unroll
            for (int dt = 0; dt < 4; ++dt) {
                bf16x8 vb = *(const bf16x8*)&VtL[(dt * 16 + t16) * 64 + cx0];
                o_acc[dt] = __builtin_amdgcn_mfma_f32_16x16x32_bf16(pa0, vb, o_acc[dt], 0, 0, 0);
            }
            bf16x8 pa1 = *(const bf16x8*)&PsL[pr + cx1];
            #pragma unroll
            for (int dt = 0; dt < 4; ++dt) {
                bf16x8 vb = *(const bf16x8*)&VtL[(dt * 16 + t16) * 64 + cx1];
                o_acc[dt] = __builtin_amdgcn_mfma_f32_16x16x32_bf16(pa1, vb, o_acc[dt], 0, 0, 0);
            }
        }
    }

    #pragma unroll
    for (int r = 0; r < 4; ++r) {
        #pragma unroll
        for (int off = 1; off < 16; off <<= 1)
            lsum[r] += __shfl_xor(lsum[r], off, 16);
    }

    // ---- epilogue: emit O in split-bf16 layout [m][hi 1024 | lo 1024], kt=h ----
    #pragma unroll
    for (int r = 0; r < 4; ++r) {
        const int row = q0 + q0w + quad * 4 + r;
        const float inv = 1.0f / lsum[r];
        short* orow = O + ((size_t)b * TS + row) * 2048;
        const int key = (quad * 4 + r) & 7;
        #pragma unroll
        for (int dt = 0; dt < 4; ++dt) {
            const float val = o_acc[dt][r] * inv;
            const int ch = 2 * dt + (t16 >> 3);
            const int pos = h * 64 + ((ch ^ key) * 8) + (t16 & 7);
            const unsigned hb = (fbits(val) + 0x8000u) & 0xffff0000u;
            orow[pos] = (short)(hb >> 16);
            orow[1024 + pos] = bf16s(val - bits2f(hb));
        }
        if (t16 == 0)
            Ls[(size_t)bh * TS + row] = lsum[r];
    }
}

// ----------------------------------------------------------------------------
// attn_avg: 1-term bf16 MFMA from pre-split swizzled Q(hi,scaled)/K(hi).
// ----------------------------------------------------------------------------
__global__ __launch_bounds__(256, 2)
void attn_avg_k(const short* __restrict__ Qs, const short* __restrict__ Ks,
                const float* __restrict__ Ls, float* __restrict__ AV)
{
    __shared__ short Qt[8192], Kt[8192];    // [128 rows][64], swizzled
    __shared__ float ML[TH][128];

    const int tid  = threadIdx.x;
    const int lane = tid & 63;
    const int wv   = tid >> 6;
    const int t16  = lane & 15;
    const int quad = lane >> 4;
    const int wq = (wv >> 1) * 64;
    const int wj = (wv & 1) * 64;

    const int j0 = blockIdx.x * 128;
    const int q0 = blockIdx.y * 128;
    const int b  = blockIdx.z;

    const int cx0 = ((quad) ^ (t16 & 7)) * 8;
    const int cx1 = ((4 + quad) ^ (t16 & 7)) * 8;

    #pragma unroll
    for (int i = 0; i < 8; ++i) {
        const int u = tid + 256 * i;
        const int h = u >> 7, r = u & 127;
        ML[h][r] = 1.0f / Ls[(size_t)(b * TH + h) * TS + q0 + r];
    }

    f32x4 acc[4][4];
    #pragma unroll
    for (int mt = 0; mt < 4; ++mt)
        #pragma unroll
        for (int nt = 0; nt < 4; ++nt) acc[mt][nt] = (f32x4){0.f, 0.f, 0.f, 0.f};

    for (int h = 0; h < TH; ++h) {
        __syncthreads();
        const size_t rbq = (size_t)(b * TH + h) * TS + q0;
        const size_t rbk = (size_t)(b * TH + h) * TS + j0;
        #pragma unroll
        for (int i = 0; i < 4; ++i) {
            const int p = i * 256 + tid;
            const int row = p >> 3;
            const int sl = (p ^ row) & 7;
            *(uint4*)&Qt[row * 64 + sl * 8] = *(const uint4*)(Qs + (rbq + row) * 128 + sl * 8);
            *(uint4*)&Kt[row * 64 + sl * 8] = *(const uint4*)(Ks + (rbk + row) * 128 + sl * 8);
        }
        __syncthreads();

        f32x4 sc[4][4];
        #pragma unroll
        for (int mt = 0; mt < 4; ++mt)
            #pragma unroll
            for (int nt = 0; nt < 4; ++nt) sc[mt][nt] = (f32x4){0.f, 0.f, 0.f, 0.f};
        #pragma unroll
        for (int ks = 0; ks < 2; ++ks) {
            const int cx = ks ? cx1 : cx0;
            bf16x8 af[4], bf[4];
            #pragma unroll
            for (int mt = 0; mt < 4; ++mt)
                af[mt] = *(const bf16x8*)&Qt[(wq + mt * 16 + t16) * 64 + cx];
            #pragma unroll
            for (int nt = 0; nt < 4; ++nt)
                bf[nt] = *(const bf16x8*)&Kt[(wj + nt * 16 + t16) * 64 + cx];
            #pragma unroll
            for (int mt = 0; mt < 4; ++mt)
                #pragma unroll
                for (int nt = 0; nt < 4; ++nt)
                    sc[mt][nt] = __builtin_amdgcn_mfma_f32_16x16x32_bf16(af[mt], bf[nt], sc[mt][nt], 0, 0, 0);
        }

        #pragma unroll
        for (int mt = 0; mt < 4; ++mt) {
            const int rl = wq + mt * 16 + quad * 4;
            const float lv[4] = {ML[h][rl], ML[h][rl + 1], ML[h][rl + 2], ML[h][rl + 3]};
            #pragma unroll
            for (int nt = 0; nt < 4; ++nt)
                #pragma unroll
                for (int r = 0; r < 4; ++r)
                    acc[mt][nt][r] = fmaf(__builtin_amdgcn_exp2f(sc[mt][nt][r]), lv[r], acc[mt][nt][r]);
        }
    }

    const float inv_h = 1.0f / (float)TH;
    #pragma unroll
    for (int mt = 0; mt < 4; ++mt) {
        #pragma unroll
        for (int r = 0; r < 4; ++r) {
            const int row = q0 + wq + mt * 16 + quad * 4 + r;
            #pragma unroll
            for (int nt = 0; nt < 4; ++nt) {
                const int col = j0 + wj + nt * 16 + t16;
                AV[((size_t)b * TS + row) * TS + col] = acc[mt][nt][r] * inv_h;
            }
        }
    }
}

// ----------------------------------------------------------------------------
extern "C" void kernel_launch(void* const* d_in, const int* in_sizes, int n_in,
                              void* d_out, int out_size, void* d_ws, size_t ws_size,
                              hipStream_t stream)
{
    const float* query = (const float*)d_in[0];
    const float* key   = (const float*)d_in[1];
    const float* value = (const float*)d_in[2];
    const float* Wq = (const float*)d_in[3];
    const float* bq = (const float*)d_in[4];
    const float* Wk = (const float*)d_in[5];
    const float* bk = (const float*)d_in[6];
    const float* Wv = (const float*)d_in[7];
    const float* bv = (const float*)d_in[8];
    const float* Wo = (const float*)d_in[9];
    const float* bo = (const float*)d_in[10];

    float* ws  = (float*)d_ws;
    float* Qr  = ws + WS_Q;       // fp32 [bh][s][64], becomes split bf16 after rope_split
    float* Kr  = ws + WS_K;
    float* Lsf = ws + WS_L;
    float* tab = ws + WS_TAB;

    float* out  = (float*)d_out;                   // [B,S,E]
    float* attn = out + (size_t)TB * TS * TE;      // [B,S,S] scratch until attn_avg
    // zone A [0,4.19M): VTs (until attn_flash), then Wo split
    // zone B [4.19M,12.58M): X splits (until gemmV), then split O (attn_flash out)
    // zone C [12.58M,16.78M): W splits for Wq/Wk/Wv
    short*    VTs  = (short*)attn;
    unsigned* WspO = (unsigned*)attn;
    unsigned* Xsp  = (unsigned*)(attn + 4194304);
    short*    Osp  = (short*)(attn + 4194304);
    unsigned* Wsp  = (unsigned*)(attn + 12582912);

    dim3 blk(256);
    dim3 gproj(TE / 128, TM_ / 128);

    rope_table<<<dim3(256), blk, 0, stream>>>(tab);

    split_rows<<<dim3(512), blk, 0, stream>>>(query, Xsp);
    split_rows<<<dim3(64),  blk, 0, stream>>>(Wq, Wsp);
    gemm3<1><<<gproj, blk, 0, stream>>>(Xsp, Wsp, bq, Qr);

    split_rows<<<dim3(512), blk, 0, stream>>>(key, Xsp);
    split_rows<<<dim3(64),  blk, 0, stream>>>(Wk, Wsp);
    gemm3<1><<<gproj, blk, 0, stream>>>(Xsp, Wsp, bk, Kr);

    split_rows<<<dim3(512), blk, 0, stream>>>(value, Xsp);
    split_rows<<<dim3(64),  blk, 0, stream>>>(Wv, Wsp);
    gemm3<2><<<gproj, blk, 0, stream>>>(Xsp, Wsp, bv, (float*)VTs);

    rope_split<<<dim3(1024), blk, 0, stream>>>(Qr, Kr, tab);

    attn_flash<<<dim3(TS / 128, TH, TB), dim3(512), 0, stream>>>(
        (const short*)Qr, (const short*)Kr, VTs, Osp, Lsf);

    split_rows<<<dim3(64), blk, 0, stream>>>(Wo, WspO);
    gemm3<0><<<gproj, blk, 0, stream>>>((const unsigned*)Osp, WspO, bo, out);

    attn_avg_k<<<dim3(TS / 128, TS / 128, TB), blk, 0, stream>>>(
        (const short*)Qr, (const short*)Kr, Lsf, attn);
}

// Round 3
// 677.346 us; speedup vs baseline: 1.3381x; 1.3381x over previous
//
#include <hip/hip_runtime.h>
#include <math.h>

// Problem constants
#define TB 4
#define TS 2048
#define TE 1024
#define TH 16
#define TD 64
#define TM_ (TB*TS)   // 8192 rows

// Workspace float offsets
#define WS_Q   0
#define WS_K   8388608
#define WS_L   16777216
#define WS_TAB 16908288

typedef __attribute__((ext_vector_type(8))) short bf16x8;  // 8 bf16 = 4 VGPRs
typedef __attribute__((ext_vector_type(4))) float f32x4;

static __device__ inline unsigned fbits(float x) {
    union { float f; unsigned u; } v; v.f = x; return v.u;
}
static __device__ inline float bits2f(unsigned u) {
    union { unsigned u; float f; } v; v.u = u; return v.f;
}
// pack [bf16(a), bf16(b)] (round-half-up) into one dword, a in low half
static __device__ inline unsigned pack_rhu(float a, float b) {
    return __builtin_amdgcn_perm(fbits(b) + 0x8000u, fbits(a) + 0x8000u, 0x07060302u);
}
static __device__ inline short bf16s(float x) {
    return (short)((fbits(x) + 0x8000u) >> 16);
}
// hi/lo split of (x0,x1): hp = packed (rounded) hi bf16s, lp = packed lo bf16s
// (h0/h1 are the ROUNDED hi values since u already includes +0x8000)
static __device__ inline void split2(float x0, float x1, unsigned& hp, unsigned& lp) {
    unsigned u0 = fbits(x0) + 0x8000u, u1 = fbits(x1) + 0x8000u;
    hp = __builtin_amdgcn_perm(u1, u0, 0x07060302u);
    float h0 = bits2f(u0 & 0xffff0000u);
    float h1 = bits2f(u1 & 0xffff0000u);
    lp = pack_rhu(x0 - h0, x1 - h1);
}

// ----------------------------------------------------------------------------
// GEMM (R1-verified): C[m,n] = sum_k X[m,k] * W[n,k] + bias[n]
// split-bf16 MFMA (3 terms), 128x128 tile, BK=32, 4 waves.
// MODE 0: fp32 out[m*N+n];  MODE 1: fp32 [B,H,S,D];  MODE 2: bf16 V^T [B,H,D,S]
// ----------------------------------------------------------------------------
template<int MODE>
__global__ __launch_bounds__(256, 2)
void gemm_nt(const float* __restrict__ X, const float* __restrict__ W,
             const float* __restrict__ bias, float* __restrict__ out)
{
    __shared__ short Ah[128][40], Al[128][40];
    __shared__ short Bh[128][40], Bl[128][40];

    const int tid  = threadIdx.x;
    const int lane = tid & 63;
    const int wv   = tid >> 6;
    const int t16  = lane & 15;
    const int quad = lane >> 4;
    const int wm   = (wv >> 1) * 64;
    const int wn   = (wv & 1) * 64;
    const int m0 = blockIdx.y * 128;
    const int n0 = blockIdx.x * 128;
    const int K = TE, N = TE;

    const int srow = tid >> 1;
    const int skc  = (tid & 1) * 16;
    const float* Xp = X + (size_t)(m0 + srow) * K + skc;
    const float* Wp = W + (size_t)(n0 + srow) * K + skc;

    f32x4 acc[4][4];
    #pragma unroll
    for (int i = 0; i < 4; ++i)
        #pragma unroll
        for (int j = 0; j < 4; ++j) acc[i][j] = (f32x4){0.f, 0.f, 0.f, 0.f};

    for (int kt = 0; kt < K; kt += 32) {
        __syncthreads();
        {
            const float* xp = Xp + kt;
            float4 x0 = *(const float4*)(xp);
            float4 x1 = *(const float4*)(xp + 4);
            float4 x2 = *(const float4*)(xp + 8);
            float4 x3 = *(const float4*)(xp + 12);
            const float* wp = Wp + kt;
            float4 w0 = *(const float4*)(wp);
            float4 w1 = *(const float4*)(wp + 4);
            float4 w2 = *(const float4*)(wp + 8);
            float4 w3 = *(const float4*)(wp + 12);

            unsigned H[8], L[8];
            split2(x0.x, x0.y, H[0], L[0]);
            split2(x0.z, x0.w, H[1], L[1]);
            split2(x1.x, x1.y, H[2], L[2]);
            split2(x1.z, x1.w, H[3], L[3]);
            split2(x2.x, x2.y, H[4], L[4]);
            split2(x2.z, x2.w, H[5], L[5]);
            split2(x3.x, x3.y, H[6], L[6]);
            split2(x3.z, x3.w, H[7], L[7]);
            *(uint4*)&Ah[srow][skc]     = make_uint4(H[0], H[1], H[2], H[3]);
            *(uint4*)&Ah[srow][skc + 8] = make_uint4(H[4], H[5], H[6], H[7]);
            *(uint4*)&Al[srow][skc]     = make_uint4(L[0], L[1], L[2], L[3]);
            *(uint4*)&Al[srow][skc + 8] = make_uint4(L[4], L[5], L[6], L[7]);

            split2(w0.x, w0.y, H[0], L[0]);
            split2(w0.z, w0.w, H[1], L[1]);
            split2(w1.x, w1.y, H[2], L[2]);
            split2(w1.z, w1.w, H[3], L[3]);
            split2(w2.x, w2.y, H[4], L[4]);
            split2(w2.z, w2.w, H[5], L[5]);
            split2(w3.x, w3.y, H[6], L[6]);
            split2(w3.z, w3.w, H[7], L[7]);
            *(uint4*)&Bh[srow][skc]     = make_uint4(H[0], H[1], H[2], H[3]);
            *(uint4*)&Bh[srow][skc + 8] = make_uint4(H[4], H[5], H[6], H[7]);
            *(uint4*)&Bl[srow][skc]     = make_uint4(L[0], L[1], L[2], L[3]);
            *(uint4*)&Bl[srow][skc + 8] = make_uint4(L[4], L[5], L[6], L[7]);
        }
        __syncthreads();

        bf16x8 ah[4], al[4], bh[4], bl[4];
        #pragma unroll
        for (int i = 0; i < 4; ++i) {
            ah[i] = *(const bf16x8*)&Ah[wm + i * 16 + t16][quad * 8];
            al[i] = *(const bf16x8*)&Al[wm + i * 16 + t16][quad * 8];
            bh[i] = *(const bf16x8*)&Bh[wn + i * 16 + t16][quad * 8];
            bl[i] = *(const bf16x8*)&Bl[wn + i * 16 + t16][quad * 8];
        }
        #pragma unroll
        for (int i = 0; i < 4; ++i)
            #pragma unroll
            for (int j = 0; j < 4; ++j) {
                acc[i][j] = __builtin_amdgcn_mfma_f32_16x16x32_bf16(ah[i], bh[j], acc[i][j], 0, 0, 0);
                acc[i][j] = __builtin_amdgcn_mfma_f32_16x16x32_bf16(al[i], bh[j], acc[i][j], 0, 0, 0);
                acc[i][j] = __builtin_amdgcn_mfma_f32_16x16x32_bf16(ah[i], bl[j], acc[i][j], 0, 0, 0);
            }
    }

    if (MODE == 2) {
        short* o16 = (short*)out;
        const int b = m0 >> 11;
        const int sbase0 = (m0 & 2047) + wm + quad * 4;
        #pragma unroll
        for (int j = 0; j < 4; ++j) {
            const int n = n0 + wn + j * 16 + t16;
            const int h = n >> 6, d = n & 63;
            const float bv = bias[n];
            const size_t base = ((size_t)(b * TH + h) * TD + d) * TS;
            #pragma unroll
            for (int i = 0; i < 4; ++i) {
                const int s = sbase0 + i * 16;
                uint2 p = make_uint2(pack_rhu(acc[i][j][0] + bv, acc[i][j][1] + bv),
                                     pack_rhu(acc[i][j][2] + bv, acc[i][j][3] + bv));
                *(uint2*)(o16 + base + s) = p;
            }
        }
        return;
    }

    #pragma unroll
    for (int j = 0; j < 4; ++j) {
        const int n = n0 + wn + j * 16 + t16;
        const float bv = bias[n];
        if (MODE == 0) {
            #pragma unroll
            for (int i = 0; i < 4; ++i)
                #pragma unroll
                for (int r = 0; r < 4; ++r) {
                    const int m = m0 + wm + i * 16 + quad * 4 + r;
                    out[(size_t)m * N + n] = acc[i][j][r] + bv;
                }
        } else {
            const int h = n >> 6, d = n & 63;
            #pragma unroll
            for (int i = 0; i < 4; ++i)
                #pragma unroll
                for (int r = 0; r < 4; ++r) {
                    const int m = m0 + wm + i * 16 + quad * 4 + r;
                    const int bb_ = m >> 11, s = m & 2047;
                    out[((size_t)(bb_ * TH + h) * TS + s) * TD + d] = acc[i][j][r] + bv;
                }
        }
    }
}

// ----------------------------------------------------------------------------
// RoPE (unchanged)
// ----------------------------------------------------------------------------
__global__ void rope_table(float* __restrict__ tab)
{
    const int idx = blockIdx.x * 256 + threadIdx.x;
    const int d = idx & 31, s = idx >> 5;
    const float e = (float)(2 * d) / 64.0f;
    const float inv = 1.0f / powf(10000.0f, e);
    const float a = (float)s * inv;
    tab[2 * idx + 0] = cosf(a);
    tab[2 * idx + 1] = sinf(a);
}

__global__ void rope_apply(float* __restrict__ Q, float* __restrict__ Kv,
                           const float* __restrict__ tab)
{
    const int idx = blockIdx.x * 256 + threadIdx.x;
    const int half = TB * TH * TS * 32;
    float* P = (idx < half) ? Q : Kv;
    const int u = idx & (half - 1);
    const int d = u & 31;
    const int s = (u >> 5) & 2047;
    const int bh = u >> 16;
    const size_t base = (size_t)bh * (TS * TD) + (size_t)s * TD;
    const float c  = tab[2 * (s * 32 + d) + 0];
    const float sn = tab[2 * (s * 32 + d) + 1];
    const float x0 = P[base + d], x1 = P[base + d + 32];
    P[base + d]      = x0 * c - x1 * sn;
    P[base + d + 32] = x1 * c + x0 * sn;
}

// ----------------------------------------------------------------------------
// Flash attention R3: R1 structure + (a) conflict-free XOR-swizzled LDS
// (measured 0 conflicts in R2), (b) XCD-clustered block remap so all 16
// q-tiles of one (b,h) share one XCD's L2 (K/V fetched once per XCD).
// fp32 Q/K in, dense fp32 O out (coalesced) — R1 epilogue.
// ----------------------------------------------------------------------------
__global__ __launch_bounds__(512, 4)
void attn_flash(const float* __restrict__ Q, const float* __restrict__ Kg,
                const short* __restrict__ VT, float* __restrict__ O,
                float* __restrict__ Ls)
{
    __shared__ short KhL[4096], KlL[4096];   // [64 rows][8 chunks of 8], swizzled
    __shared__ short VtL[4096];              // V^T tile [d][j-chunks], swizzled
    __shared__ short PsL[8192];              // P [128 rows][8 chunks], swizzled

    const int tid  = threadIdx.x;
    const int lane = tid & 63;
    const int wv   = tid >> 6;        // wave 0..7
    const int t16  = lane & 15;
    const int quad = lane >> 4;
    const int q0w  = wv * 16;

    // XCD-clustered remap: linear id L -> (q-tile, h, b) such that all 16
    // q-tiles of a (h,b) group have L = xcd (mod 8) -> same XCD L2.
    const int L   = blockIdx.x + 16 * blockIdx.y + 256 * blockIdx.z;
    const int xcd = L & 7;
    const int i_  = L >> 3;                 // 0..127
    const int qt  = i_ & 15;                // q-tile
    const int g   = (xcd << 3) | (i_ >> 4); // 0..63 group, g>>3 == xcd
    const int h   = g & 15;
    const int b   = g >> 4;

    const int q0 = qt * 128;
    const int bh = b * TH + h;
    const size_t hoff = (size_t)bh * TS * TD;
    const float* Kr = Kg + hoff;
    const short* Vth = VT + (size_t)bh * TD * TS;

    // chunk offsets (shorts) for swizzled LDS reads: slot = chunk ^ (row&7)
    const int cx0 = ((quad) ^ (t16 & 7)) * 8;       // ks=0: chunk = quad
    const int cx1 = ((4 + quad) ^ (t16 & 7)) * 8;   // ks=1: chunk = 4+quad

    // ---- Q fragments straight from global, scaled by 0.125*log2(e), split ----
    const float qsc = 0.125f * 1.44269504f;
    bf16x8 qfh[2], qfl[2];
    {
        const float* qp = Q + hoff + (size_t)(q0 + q0w + t16) * TD;
        #pragma unroll
        for (int ks = 0; ks < 2; ++ks) {
            float4 a = *(const float4*)(qp + ks * 32 + quad * 8);
            float4 c = *(const float4*)(qp + ks * 32 + quad * 8 + 4);
            union { unsigned u[4]; bf16x8 v; } H, Lo;
            split2(a.x * qsc, a.y * qsc, H.u[0], Lo.u[0]);
            split2(a.z * qsc, a.w * qsc, H.u[1], Lo.u[1]);
            split2(c.x * qsc, c.y * qsc, H.u[2], Lo.u[2]);
            split2(c.z * qsc, c.w * qsc, H.u[3], Lo.u[3]);
            qfh[ks] = H.v; qfl[ks] = Lo.v;
        }
    }

    float lsum[4] = {0.f, 0.f, 0.f, 0.f};
    f32x4 o_acc[4];
    #pragma unroll
    for (int dt = 0; dt < 4; ++dt) o_acc[dt] = (f32x4){0.f, 0.f, 0.f, 0.f};

    // staging indices (512 threads): row = tid>>3 (0..63), chunk = tid&7
    const int krow = tid >> 3;
    const int kch  = tid & 7;
    const int ksl  = (kch ^ (krow & 7)) * 8;   // swizzled slot (shorts)

    for (int j0 = 0; j0 < TS; j0 += 64) {
        __syncthreads();
        {
            const float* kp = Kr + (size_t)(j0 + krow) * TD + kch * 8;
            float4 a = *(const float4*)kp;
            float4 c = *(const float4*)(kp + 4);
            unsigned H[4], Lo[4];
            split2(a.x, a.y, H[0], Lo[0]);
            split2(a.z, a.w, H[1], Lo[1]);
            split2(c.x, c.y, H[2], Lo[2]);
            split2(c.z, c.w, H[3], Lo[3]);
            *(uint4*)&KhL[krow * 64 + ksl] = make_uint4(H[0], H[1], H[2], H[3]);
            *(uint4*)&KlL[krow * 64 + ksl] = make_uint4(Lo[0], Lo[1], Lo[2], Lo[3]);
            uint4 vv = *(const uint4*)(Vth + (size_t)krow * TS + j0 + kch * 8);
            *(uint4*)&VtL[krow * 64 + ksl] = vv;
        }
        __syncthreads();

        // ---- scores: 4 j-subtiles x 2 ksteps x 3 split terms ----
        f32x4 sc[4];
        #pragma unroll
        for (int t = 0; t < 4; ++t) sc[t] = (f32x4){0.f, 0.f, 0.f, 0.f};
        #pragma unroll
        for (int t = 0; t < 4; ++t) {
            const int rb = (t * 16 + t16) * 64;
            bf16x8 kh0 = *(const bf16x8*)&KhL[rb + cx0];
            bf16x8 kl0 = *(const bf16x8*)&KlL[rb + cx0];
            sc[t] = __builtin_amdgcn_mfma_f32_16x16x32_bf16(qfh[0], kh0, sc[t], 0, 0, 0);
            sc[t] = __builtin_amdgcn_mfma_f32_16x16x32_bf16(qfh[0], kl0, sc[t], 0, 0, 0);
            sc[t] = __builtin_amdgcn_mfma_f32_16x16x32_bf16(qfl[0], kh0, sc[t], 0, 0, 0);
            bf16x8 kh1 = *(const bf16x8*)&KhL[rb + cx1];
            bf16x8 kl1 = *(const bf16x8*)&KlL[rb + cx1];
            sc[t] = __builtin_amdgcn_mfma_f32_16x16x32_bf16(qfh[1], kh1, sc[t], 0, 0, 0);
            sc[t] = __builtin_amdgcn_mfma_f32_16x16x32_bf16(qfh[1], kl1, sc[t], 0, 0, 0);
            sc[t] = __builtin_amdgcn_mfma_f32_16x16x32_bf16(qfl[1], kh1, sc[t], 0, 0, 0);
        }

        // ---- p = exp2(s'), accumulate l, write P to swizzled LDS ----
        #pragma unroll
        for (int t = 0; t < 4; ++t) {
            float p0 = __builtin_amdgcn_exp2f(sc[t][0]);
            float p1 = __builtin_amdgcn_exp2f(sc[t][1]);
            float p2 = __builtin_amdgcn_exp2f(sc[t][2]);
            float p3 = __builtin_amdgcn_exp2f(sc[t][3]);
            lsum[0] += p0; lsum[1] += p1; lsum[2] += p2; lsum[3] += p3;
            const int cb = 2 * t + (t16 >> 3);
            const int co = t16 & 7;
            const int r0 = q0w + quad * 4;
            PsL[(r0 + 0) * 64 + ((cb ^ ((r0 + 0) & 7)) * 8) + co] = bf16s(p0);
            PsL[(r0 + 1) * 64 + ((cb ^ ((r0 + 1) & 7)) * 8) + co] = bf16s(p1);
            PsL[(r0 + 2) * 64 + ((cb ^ ((r0 + 2) & 7)) * 8) + co] = bf16s(p2);
            PsL[(r0 + 3) * 64 + ((cb ^ ((r0 + 3) & 7)) * 8) + co] = bf16s(p3);
        }

        // ---- PV: o += P * V (intra-wave Ps rows) ----
        {
            const int pr = (q0w + t16) * 64;
            bf16x8 pa0 = *(const bf16x8*)&PsL[pr + cx0];
            #pragma unroll
            for (int dt = 0; dt < 4; ++dt) {
                bf16x8 vb = *(const bf16x8*)&VtL[(dt * 16 + t16) * 64 + cx0];
                o_acc[dt] = __builtin_amdgcn_mfma_f32_16x16x32_bf16(pa0, vb, o_acc[dt], 0, 0, 0);
            }
            bf16x8 pa1 = *(const bf16x8*)&PsL[pr + cx1];
            #pragma unroll
            for (int dt = 0; dt < 4; ++dt) {
                bf16x8 vb = *(const bf16x8*)&VtL[(dt * 16 + t16) * 64 + cx1];
                o_acc[dt] = __builtin_amdgcn_mfma_f32_16x16x32_bf16(pa1, vb, o_acc[dt], 0, 0, 0);
            }
        }
    }

    // ---- reduce l over the 16 t16 lanes ----
    #pragma unroll
    for (int r = 0; r < 4; ++r) {
        #pragma unroll
        for (int off = 1; off < 16; off <<= 1)
            lsum[r] += __shfl_xor(lsum[r], off, 16);
    }

    // ---- epilogue (R1): dense fp32 O[b,s,h*64+d] = o/l; save l ----
    #pragma unroll
    for (int r = 0; r < 4; ++r) {
        const int row = q0 + q0w + quad * 4 + r;
        const float inv = 1.0f / lsum[r];
        #pragma unroll
        for (int dt = 0; dt < 4; ++dt)
            O[((size_t)(b * TS) + row) * TE + h * TD + dt * 16 + t16] = o_acc[dt][r] * inv;
        if (t16 == 0)
            Ls[(size_t)bh * TS + row] = lsum[r];
    }
}

// ----------------------------------------------------------------------------
// attn_avg with MFMA (unchanged from R1)
// ----------------------------------------------------------------------------
__global__ __launch_bounds__(256, 2)
void attn_avg_k(const float* __restrict__ Q, const float* __restrict__ Kg,
                const float* __restrict__ Ls, float* __restrict__ AV)
{
    __shared__ short Qt[128][72];
    __shared__ short Kt[128][72];
    __shared__ float ML[TH][128];

    const int tid  = threadIdx.x;
    const int lane = tid & 63;
    const int wv   = tid >> 6;
    const int t16  = lane & 15;
    const int quad = lane >> 4;
    const int wq = (wv >> 1) * 64;
    const int wj = (wv & 1) * 64;

    const int j0 = blockIdx.x * 128;
    const int q0 = blockIdx.y * 128;
    const int b  = blockIdx.z;

    #pragma unroll
    for (int i = 0; i < 8; ++i) {
        const int u = tid + 256 * i;
        const int h = u >> 7, r = u & 127;
        ML[h][r] = 1.0f / Ls[(size_t)(b * TH + h) * TS + q0 + r];
    }

    f32x4 acc[4][4];
    #pragma unroll
    for (int mt = 0; mt < 4; ++mt)
        #pragma unroll
        for (int nt = 0; nt < 4; ++nt) acc[mt][nt] = (f32x4){0.f, 0.f, 0.f, 0.f};

    const float qscale = 0.125f * 1.44269504f;

    for (int h = 0; h < TH; ++h) {
        __syncthreads();
        const size_t hoff = (size_t)(b * TH + h) * TS * TD;
        #pragma unroll
        for (int i = 0; i < 8; ++i) {
            const int f = tid + 256 * i;
            const int row = f >> 4;
            const int dq = (f & 15) * 4;
            float4 qv = *(const float4*)(Q + hoff + (size_t)(q0 + row) * TD + dq);
            uint2 qp = make_uint2(pack_rhu(qv.x * qscale, qv.y * qscale),
                                  pack_rhu(qv.z * qscale, qv.w * qscale));
            *(uint2*)&Qt[row][dq] = qp;
            float4 kv = *(const float4*)(Kg + hoff + (size_t)(j0 + row) * TD + dq);
            uint2 kp = make_uint2(pack_rhu(kv.x, kv.y), pack_rhu(kv.z, kv.w));
            *(uint2*)&Kt[row][dq] = kp;
        }
        __syncthreads();

        f32x4 sc[4][4];
        #pragma unroll
        for (int mt = 0; mt < 4; ++mt)
            #pragma unroll
            for (int nt = 0; nt < 4; ++nt) sc[mt][nt] = (f32x4){0.f, 0.f, 0.f, 0.f};
        #pragma unroll
        for (int ks = 0; ks < 2; ++ks) {
            bf16x8 af[4], bf[4];
            #pragma unroll
            for (int mt = 0; mt < 4; ++mt)
                af[mt] = *(const bf16x8*)&Qt[wq + mt * 16 + t16][ks * 32 + quad * 8];
            #pragma unroll
            for (int nt = 0; nt < 4; ++nt)
                bf[nt] = *(const bf16x8*)&Kt[wj + nt * 16 + t16][ks * 32 + quad * 8];
            #pragma unroll
            for (int mt = 0; mt < 4; ++mt)
                #pragma unroll
                for (int nt = 0; nt < 4; ++nt)
                    sc[mt][nt] = __builtin_amdgcn_mfma_f32_16x16x32_bf16(af[mt], bf[nt], sc[mt][nt], 0, 0, 0);
        }

        #pragma unroll
        for (int mt = 0; mt < 4; ++mt) {
            const int rl = wq + mt * 16 + quad * 4;
            const float lv[4] = {ML[h][rl], ML[h][rl + 1], ML[h][rl + 2], ML[h][rl + 3]};
            #pragma unroll
            for (int nt = 0; nt < 4; ++nt)
                #pragma unroll
                for (int r = 0; r < 4; ++r)
                    acc[mt][nt][r] = fmaf(__builtin_amdgcn_exp2f(sc[mt][nt][r]), lv[r], acc[mt][nt][r]);
        }
    }

    const float inv_h = 1.0f / (float)TH;
    #pragma unroll
    for (int mt = 0; mt < 4; ++mt) {
        #pragma unroll
        for (int r = 0; r < 4; ++r) {
            const int row = q0 + wq + mt * 16 + quad * 4 + r;
            #pragma unroll
            for (int nt = 0; nt < 4; ++nt) {
                const int col = j0 + wj + nt * 16 + t16;
                AV[((size_t)b * TS + row) * TS + col] = acc[mt][nt][r] * inv_h;
            }
        }
    }
}

// ----------------------------------------------------------------------------
extern "C" void kernel_launch(void* const* d_in, const int* in_sizes, int n_in,
                              void* d_out, int out_size, void* d_ws, size_t ws_size,
                              hipStream_t stream)
{
    const float* query = (const float*)d_in[0];
    const float* key   = (const float*)d_in[1];
    const float* value = (const float*)d_in[2];
    const float* Wq = (const float*)d_in[3];
    const float* bq = (const float*)d_in[4];
    const float* Wk = (const float*)d_in[5];
    const float* bk = (const float*)d_in[6];
    const float* Wv = (const float*)d_in[7];
    const float* bv = (const float*)d_in[8];
    const float* Wo = (const float*)d_in[9];
    const float* bo = (const float*)d_in[10];

    float* ws  = (float*)d_ws;
    float* Qr  = ws + WS_Q;       // RoPE'd Q fp32 [B,H,S,D]
    float* Kr  = ws + WS_K;       // RoPE'd K fp32 [B,H,S,D]
    float* Lsf = ws + WS_L;       // softmax denominators [B,H,S]
    float* tab = ws + WS_TAB;     // cos/sin

    float* out  = (float*)d_out;                   // [B,S,E]
    float* attn = out + (size_t)TB * TS * TE;      // [B,S,S] (written last)
    short* VT = (short*)attn;                      // bf16 [B,H,D,S] = 4.2M floats
    float* Ow = attn + 4194304;                    // fp32 [B,S,E]   = 8.4M floats

    dim3 blk(256);
    dim3 gproj(TE / 128, TM_ / 128);

    gemm_nt<1><<<gproj, blk, 0, stream>>>(query, Wq, bq, Qr);
    gemm_nt<1><<<gproj, blk, 0, stream>>>(key,   Wk, bk, Kr);
    gemm_nt<2><<<gproj, blk, 0, stream>>>(value, Wv, bv, (float*)VT);
    rope_table<<<dim3(256), blk, 0, stream>>>(tab);
    rope_apply<<<dim3(32768), blk, 0, stream>>>(Qr, Kr, tab);
    attn_flash<<<dim3(TS / 128, TH, TB), dim3(512), 0, stream>>>(Qr, Kr, VT, Ow, Lsf);
    gemm_nt<0><<<gproj, blk, 0, stream>>>(Ow, Wo, bo, out);
    attn_avg_k<<<dim3(TS / 128, TS / 128, TB), blk, 0, stream>>>(Qr, Kr, Lsf, attn);
}